// Round 1
// baseline (279.846 us; speedup 1.0000x reference)
//
#include <hip/hip_runtime.h>
#include <hip/hip_bf16.h>
#include <math.h>

#define NROWS 131072
#define NCOLS 360            // 90 float4 per row
#define WAVES_PER_BLOCK 4

// One wave (64 lanes) per row. Row = 90 float4: lane i holds f4[i], and
// lanes 0..25 additionally hold f4[64+i]. Single global read of preds.
__global__ __launch_bounds__(256) void viewpoint_row_kernel(
    const float* __restrict__ preds,
    const int* __restrict__ labels,
    float* __restrict__ partial)   // one partial sum per block
{
    const int wave = threadIdx.x >> 6;
    const int lane = threadIdx.x & 63;
    const int row  = blockIdx.x * WAVES_PER_BLOCK + wave;

    const float* p = preds + (size_t)row * NCOLS;       // row start is 16B aligned (1440 B stride)
    const float4* p4 = (const float4*)p;

    float4 a0 = p4[lane];
    float4 a1 = make_float4(0.f, 0.f, 0.f, 0.f);
    const bool have2 = lane < (90 - 64);                // lanes 0..25
    if (have2) a1 = p4[64 + lane];

    // ---- pass over registers: sum |x| and max(x) ----
    float s = fabsf(a0.x) + fabsf(a0.y) + fabsf(a0.z) + fabsf(a0.w);
    float m = fmaxf(fmaxf(a0.x, a0.y), fmaxf(a0.z, a0.w));
    if (have2) {
        s += fabsf(a1.x) + fabsf(a1.y) + fabsf(a1.z) + fabsf(a1.w);
        m = fmaxf(m, fmaxf(fmaxf(a1.x, a1.y), fmaxf(a1.z, a1.w)));
    }
    // wave-wide butterfly reduction (64 lanes)
    #pragma unroll
    for (int off = 32; off > 0; off >>= 1) {
        s += __shfl_xor(s, off);
        m = fmaxf(m, __shfl_xor(m, off));
    }

    const float inv = 1.0f / s;

    // ---- sum exp((x - m) / s1) from registers ----
    float e = expf((a0.x - m) * inv) + expf((a0.y - m) * inv)
            + expf((a0.z - m) * inv) + expf((a0.w - m) * inv);
    if (have2) {
        e += expf((a1.x - m) * inv) + expf((a1.y - m) * inv)
           + expf((a1.z - m) * inv) + expf((a1.w - m) * inv);
    }
    #pragma unroll
    for (int off = 32; off > 0; off >>= 1) e += __shfl_xor(e, off);

    // ---- gathered log-prob for this row's label ----
    float g = 0.f;
    if (lane == 0) {
        const int lab = labels[row];
        const float xl = p[lab];                        // L1/L2-hot: row just streamed
        g = (xl - m) * inv - logf(e);
    }

    // ---- block reduction (4 waves) -> one partial per block ----
    __shared__ float sh[WAVES_PER_BLOCK];
    if (lane == 0) sh[wave] = g;
    __syncthreads();
    if (threadIdx.x == 0)
        partial[blockIdx.x] = sh[0] + sh[1] + sh[2] + sh[3];
}

// Single-block final reduction of per-block partials.
__global__ __launch_bounds__(256) void viewpoint_final_kernel(
    const float* __restrict__ partial, float* __restrict__ out, int n)
{
    float s = 0.f;
    for (int i = threadIdx.x; i < n; i += 256) s += partial[i];
    #pragma unroll
    for (int off = 32; off > 0; off >>= 1) s += __shfl_xor(s, off);
    __shared__ float sh[4];
    if ((threadIdx.x & 63) == 0) sh[threadIdx.x >> 6] = s;
    __syncthreads();
    if (threadIdx.x == 0)
        out[0] = -(sh[0] + sh[1] + sh[2] + sh[3]) * (1.0f / (float)NCOLS);
}

extern "C" void kernel_launch(void* const* d_in, const int* in_sizes, int n_in,
                              void* d_out, int out_size, void* d_ws, size_t ws_size,
                              hipStream_t stream) {
    const float* preds  = (const float*)d_in[0];
    const int*   labels = (const int*)d_in[1];
    float* out = (float*)d_out;
    float* partial = (float*)d_ws;                      // 32768 floats = 128 KB

    const int nblocks = NROWS / WAVES_PER_BLOCK;        // 32768
    viewpoint_row_kernel<<<nblocks, 256, 0, stream>>>(preds, labels, partial);
    viewpoint_final_kernel<<<1, 256, 0, stream>>>(partial, out, nblocks);
}

// Round 2
// 254.405 us; speedup vs baseline: 1.1000x; 1.1000x over previous
//
#include <hip/hip_runtime.h>
#include <hip/hip_bf16.h>
#include <math.h>

#define NROWS 131072
#define NCOLS 360               // 90 float4 per row
#define ROWS_PER_WAVE 8
#define NWAVES (NROWS / ROWS_PER_WAVE)      // 16384
#define NBLOCKS (NWAVES / 4)                // 4096

typedef float f32x4 __attribute__((ext_vector_type(4)));

// One wave per row, 8 rows per wave (interleaved by NWAVES so concurrent
// waves touch adjacent rows). Row = 90 float4: lane i holds f4[i], lanes
// 0..25 also f4[64+i]. Single streaming read of preds, no max-subtraction
// (|x|/sum|x| is in [-1,1] so exp is always safe), native exp/log.
__global__ __launch_bounds__(256) void viewpoint_row_kernel(
    const float* __restrict__ preds,
    const int* __restrict__ labels,
    float* __restrict__ partial)
{
    const int wave = threadIdx.x >> 6;
    const int lane = threadIdx.x & 63;
    const int wgid = blockIdx.x * 4 + wave;            // 0..NWAVES-1
    const bool have2 = lane < (90 - 64);               // lanes 0..25

    float gacc = 0.f;

    #pragma unroll
    for (int r = 0; r < ROWS_PER_WAVE; ++r) {
        const int row = r * NWAVES + wgid;
        const f32x4* p4 = (const f32x4*)(preds + (size_t)row * NCOLS);

        f32x4 a0 = __builtin_nontemporal_load(p4 + lane);
        f32x4 a1 = {0.f, 0.f, 0.f, 0.f};
        if (have2) a1 = __builtin_nontemporal_load(p4 + 64 + lane);

        // ---- sum |x| (abs folds into VOP3 input modifiers) ----
        float s = (fabsf(a0.x) + fabsf(a0.y)) + (fabsf(a0.z) + fabsf(a0.w))
                + ((fabsf(a1.x) + fabsf(a1.y)) + (fabsf(a1.z) + fabsf(a1.w)));
        #pragma unroll
        for (int off = 32; off > 0; off >>= 1) s += __shfl_xor(s, off);

        const float inv = __builtin_amdgcn_rcpf(s);

        // ---- sum exp(x * inv); args bounded in [-1,1], no max needed ----
        float e = (__expf(a0.x * inv) + __expf(a0.y * inv))
                + (__expf(a0.z * inv) + __expf(a0.w * inv));
        if (have2)
            e += (__expf(a1.x * inv) + __expf(a1.y * inv))
               + (__expf(a1.z * inv) + __expf(a1.w * inv));
        #pragma unroll
        for (int off = 32; off > 0; off >>= 1) e += __shfl_xor(e, off);

        // ---- x[label] from registers (labels[row] is wave-uniform) ----
        const int lab = labels[row];
        const int f4i = lab >> 2;
        const int c   = lab & 3;
        const f32x4 src = (f4i < 64) ? a0 : a1;        // uniform select
        const int owner = (f4i < 64) ? f4i : (f4i - 64);
        const float v = (c == 0) ? src.x : (c == 1) ? src.y
                      : (c == 2) ? src.z : src.w;
        const float xl = __shfl(v, owner);

        gacc += xl * inv - __logf(e);
    }

    __shared__ float sh[4];
    if (lane == 0) sh[wave] = gacc;
    __syncthreads();
    if (threadIdx.x == 0)
        partial[blockIdx.x] = sh[0] + sh[1] + sh[2] + sh[3];
}

__global__ __launch_bounds__(256) void viewpoint_final_kernel(
    const float* __restrict__ partial, float* __restrict__ out, int n)
{
    float s = 0.f;
    for (int i = threadIdx.x; i < n; i += 256) s += partial[i];
    #pragma unroll
    for (int off = 32; off > 0; off >>= 1) s += __shfl_xor(s, off);
    __shared__ float sh[4];
    if ((threadIdx.x & 63) == 0) sh[threadIdx.x >> 6] = s;
    __syncthreads();
    if (threadIdx.x == 0)
        out[0] = -(sh[0] + sh[1] + sh[2] + sh[3]) * (1.0f / (float)NCOLS);
}

extern "C" void kernel_launch(void* const* d_in, const int* in_sizes, int n_in,
                              void* d_out, int out_size, void* d_ws, size_t ws_size,
                              hipStream_t stream) {
    const float* preds  = (const float*)d_in[0];
    const int*   labels = (const int*)d_in[1];
    float* out = (float*)d_out;
    float* partial = (float*)d_ws;                      // 4096 floats = 16 KB

    viewpoint_row_kernel<<<NBLOCKS, 256, 0, stream>>>(preds, labels, partial);
    viewpoint_final_kernel<<<1, 256, 0, stream>>>(partial, out, NBLOCKS);
}